// Round 3
// baseline (3928.533 us; speedup 1.0000x reference)
//
#include <hip/hip_runtime.h>

// ---------------------------------------------------------------------------
// ATKT forward on MI355X.
// prep (bf16 weight convert + W1-lo split + flag zero) -> interaction embed ->
// xg GEMM (bf16 MFMA, f32 out) -> 16-WG weight-stationary LSTM (h hi/lo split,
// global release/acquire barrier) -> score GEMM -> softmax prefix scan
// (attn_out bf16) -> fc GEMM producing p=attn_out*W1^T (W1 split) and
// q=lstm_out*W2^T+b in f32 -> exact f32 prefix scan + sigmoid into d_out.
// ---------------------------------------------------------------------------

typedef __attribute__((ext_vector_type(4))) float f32x4;
typedef __attribute__((ext_vector_type(8))) short s16x8;
typedef __attribute__((ext_vector_type(4))) short s16x4;

__device__ __forceinline__ unsigned short f2b(float f) {
  unsigned u = __float_as_uint(f);
  u += 0x7FFFu + ((u >> 16) & 1u);
  return (unsigned short)(u >> 16);
}
__device__ __forceinline__ float b2f(unsigned short s) {
  return __uint_as_float(((unsigned)s) << 16);
}
__device__ __forceinline__ float sigf(float x) {
  return __builtin_amdgcn_rcpf(1.f + __expf(-x));
}
__device__ __forceinline__ float tanhf_(float x) {
  return 1.f - 2.f * __builtin_amdgcn_rcpf(1.f + __expf(2.f * x));
}

// --- prep: bf16 conversions + fc_W1 lo-residual + zero LSTM flags -----------
__global__ void prep_kernel(const float* __restrict__ W_ih,
                            const float* __restrict__ fc_W,
                            const float* __restrict__ mlp_W,
                            unsigned short* __restrict__ wihb,
                            unsigned short* __restrict__ fcwb,
                            unsigned short* __restrict__ mlpwb,
                            unsigned short* __restrict__ fcw1lo,
                            int* __restrict__ flags) {
  int i = blockIdx.x * 256 + threadIdx.x;
  if (i < 524288) {
    wihb[i] = f2b(W_ih[i]);
  } else if (i < 1048576) {
    int j = i - 524288;
    float w = fc_W[j];
    unsigned short h = f2b(w);
    fcwb[j] = h;
    int col = j & 511;
    if (col < 256) fcw1lo[(size_t)(j >> 9) * 256 + col] = f2b(w - b2f(h));
  } else if (i < 1114112) {
    mlpwb[i - 1048576] = f2b(mlp_W[i - 1048576]);
  }
  if (i < 1024) flags[i] = 0;
}

// --- interaction embedding: [BT][512] bf16 ----------------------------------
__global__ void interact_kernel(const int* __restrict__ cseq,
                                const int* __restrict__ kseq,
                                const float* __restrict__ embC,
                                const float* __restrict__ embR,
                                unsigned short* __restrict__ inter) {
  int bt = blockIdx.x * 4 + (threadIdx.x >> 6);
  int l = threadIdx.x & 63;
  int c = cseq[bt], k = kseq[bt];
  const float* h1 = k ? (embC + (size_t)c * 256) : embR;          // first half
  const float* h2 = k ? (embR + 256) : (embC + (size_t)c * 256);  // second half
  int seg = l * 8;
  const float* src = (seg < 256) ? (h1 + seg) : (h2 + (seg - 256));
  s16x8 vv;
#pragma unroll
  for (int q = 0; q < 8; ++q) vv[q] = (short)f2b(src[q]);
  *(s16x8*)(inter + (size_t)bt * 512 + seg) = vv;
}

// --- xg GEMM: xg[M][1024](f32) = A[M][512](bf16) x W[1024][512]^T + b1+b2 ---
__global__ __launch_bounds__(256, 2) void gemm_xg(
    const unsigned short* __restrict__ A, const unsigned short* __restrict__ W,
    const float* __restrict__ bias1, const float* __restrict__ bias2,
    float* __restrict__ outp) {
  constexpr int KW = 512;
  __shared__ char smem[20480];
  char* As = smem;          // [128][80B]
  char* Ws = smem + 10240;  // [128][80B]
  const int tn = blockIdx.x, tm = blockIdx.y;
  const int tid = threadIdx.x;
  const int v = tid >> 6, l = tid & 63;
  const int wm = v >> 1, wn = v & 1;
  const int lr = l & 15, lh = l >> 4;

  f32x4 acc[4][4];
#pragma unroll
  for (int i = 0; i < 4; ++i)
#pragma unroll
    for (int jj = 0; jj < 4; ++jj) acc[i][jj] = f32x4{0.f, 0.f, 0.f, 0.f};

  const unsigned short* Ag = A + (size_t)(tm * 128) * KW;
  const unsigned short* Wg = W + (size_t)(tn * 128) * KW;

  s16x8 ra[2], rw[2];
#pragma unroll
  for (int q = 0; q < 2; ++q) {
    int slot = q * 256 + tid, row = slot >> 2, c16 = slot & 3;
    ra[q] = *(const s16x8*)(Ag + (size_t)row * KW + c16 * 8);
    rw[q] = *(const s16x8*)(Wg + (size_t)row * KW + c16 * 8);
  }
  for (int kk = 0; kk < KW / 32; ++kk) {
#pragma unroll
    for (int q = 0; q < 2; ++q) {
      int slot = q * 256 + tid, row = slot >> 2, c16 = slot & 3;
      *(s16x8*)(As + row * 80 + c16 * 16) = ra[q];
      *(s16x8*)(Ws + row * 80 + c16 * 16) = rw[q];
    }
    __syncthreads();
    if (kk + 1 < KW / 32) {
#pragma unroll
      for (int q = 0; q < 2; ++q) {
        int slot = q * 256 + tid, row = slot >> 2, c16 = slot & 3;
        ra[q] = *(const s16x8*)(Ag + (size_t)row * KW + (kk + 1) * 32 + c16 * 8);
        rw[q] = *(const s16x8*)(Wg + (size_t)row * KW + (kk + 1) * 32 + c16 * 8);
      }
    }
    s16x8 af[4], wf[4];
#pragma unroll
    for (int mt = 0; mt < 4; ++mt) {
      int r = wm * 64 + mt * 16 + lr;
      af[mt] = *(const s16x8*)(As + r * 80 + lh * 16);
    }
#pragma unroll
    for (int nt = 0; nt < 4; ++nt) {
      int n = wn * 64 + nt * 16 + lr;
      wf[nt] = *(const s16x8*)(Ws + n * 80 + lh * 16);
    }
#pragma unroll
    for (int mt = 0; mt < 4; ++mt)
#pragma unroll
      for (int nt = 0; nt < 4; ++nt)
        acc[mt][nt] =
            __builtin_amdgcn_mfma_f32_16x16x32_bf16(af[mt], wf[nt], acc[mt][nt], 0, 0, 0);
    __syncthreads();
  }
#pragma unroll
  for (int mt = 0; mt < 4; ++mt) {
#pragma unroll
    for (int nt = 0; nt < 4; ++nt) {
      int col = tn * 128 + wn * 64 + nt * 16 + lr;
      float bv = bias1[col] + bias2[col];
#pragma unroll
      for (int vi = 0; vi < 4; ++vi) {
        int row = tm * 128 + wm * 64 + mt * 16 + lh * 4 + vi;
        outp[(size_t)row * 1024 + col] = acc[mt][nt][vi] + bv;
      }
    }
  }
}

// --- LSTM: 16 WGs, W_hh resident in VGPRs, h exchanged as bf16 hi+lo --------
__global__ __launch_bounds__(256, 1) void lstm_kernel(
    const float* __restrict__ W_hh, const float* __restrict__ xg,
    unsigned short* __restrict__ hbuf_hi, unsigned short* __restrict__ hbuf_lo,
    unsigned short* __restrict__ lstm_out, int* __restrict__ flags) {
  const int w = blockIdx.x, tid = threadIdx.x;
  const int g = w >> 2, j = w & 3;
  const int v = tid >> 6, l = tid & 63;
  const int ww = (w << 2) | v;  // wave flag id 0..63
  const int lr = l & 15, lh = l >> 4;

  // W_hh slice as MFMA A-fragments in registers (bf16).
  s16x8 wf[4][8];
#pragma unroll
  for (int gt = 0; gt < 4; ++gt) {
    const float* wr = W_hh + (size_t)(gt * 256 + j * 64 + v * 16 + lr) * 256;
#pragma unroll
    for (int kc = 0; kc < 8; ++kc) {
      const float* p = wr + kc * 32 + lh * 8;
      s16x8 t;
#pragma unroll
      for (int q = 0; q < 8; ++q) t[q] = (short)f2b(p[q]);
      wf[gt][kc] = t;
    }
  }
  const int bcol = g * 16 + lr;                // batch (D-layout col = l&15)
  const int dbase = j * 64 + v * 16 + lh * 4;  // D-layout row base (+vi)
  const float* xgp = xg + (size_t)bcol * 512 * 1024 + dbase;
  float cst[4] = {0.f, 0.f, 0.f, 0.f};

  f32x4 xpre[4];
#pragma unroll
  for (int gt = 0; gt < 4; ++gt) xpre[gt] = *(const f32x4*)(xgp + gt * 256);

  for (int t = 0; t < 512; ++t) {
    f32x4 acc[4];
#pragma unroll
    for (int gt = 0; gt < 4; ++gt) acc[gt] = xpre[gt];
    if (t > 0) {
      int* f = flags + l * 16;
      while (1) {
        int fv = __hip_atomic_load(f, __ATOMIC_ACQUIRE, __HIP_MEMORY_SCOPE_AGENT);
        if (__all(fv >= t)) break;
        __builtin_amdgcn_s_sleep(1);
      }
      size_t hb_off = ((size_t)(((t - 1) & 1) * 4 + g) * 16 + lr) * 256;
      s16x8 hf_hi[8], hf_lo[8];
#pragma unroll
      for (int kc = 0; kc < 8; ++kc) {
        hf_hi[kc] = *(const s16x8*)(hbuf_hi + hb_off + kc * 32 + lh * 8);
        hf_lo[kc] = *(const s16x8*)(hbuf_lo + hb_off + kc * 32 + lh * 8);
      }
#pragma unroll
      for (int gt = 0; gt < 4; ++gt) {
#pragma unroll
        for (int kc = 0; kc < 8; ++kc)
          acc[gt] = __builtin_amdgcn_mfma_f32_16x16x32_bf16(wf[gt][kc], hf_hi[kc],
                                                            acc[gt], 0, 0, 0);
#pragma unroll
        for (int kc = 0; kc < 8; ++kc)
          acc[gt] = __builtin_amdgcn_mfma_f32_16x16x32_bf16(wf[gt][kc], hf_lo[kc],
                                                            acc[gt], 0, 0, 0);
      }
    }
    if (t < 511) {  // prefetch next step's input gates
#pragma unroll
      for (int gt = 0; gt < 4; ++gt)
        xpre[gt] = *(const f32x4*)(xgp + (size_t)(t + 1) * 1024 + gt * 256);
    }
    s16x4 hhi, hlo;
#pragma unroll
    for (int vi = 0; vi < 4; ++vi) {
      float ig = sigf(acc[0][vi]);
      float fg = sigf(acc[1][vi]);
      float gg = tanhf_(acc[2][vi]);
      float og = sigf(acc[3][vi]);
      cst[vi] = fg * cst[vi] + ig * gg;
      float hv = og * tanhf_(cst[vi]);
      unsigned short hb = f2b(hv);
      hhi[vi] = (short)hb;
      hlo[vi] = (short)f2b(hv - b2f(hb));
    }
    size_t wo = ((size_t)((t & 1) * 4 + g) * 16 + lr) * 256 + dbase;
    *(s16x4*)(hbuf_hi + wo) = hhi;
    *(s16x4*)(hbuf_lo + wo) = hlo;
    *(s16x4*)(lstm_out + ((size_t)bcol * 512 + t) * 256 + dbase) = hhi;
    if (l == 0)
      __hip_atomic_store(flags + ww * 16, t + 1, __ATOMIC_RELEASE,
                         __HIP_MEMORY_SCOPE_AGENT);
  }
}

// --- score GEMM: score[bt] = sum_a tanh(H mlpW^T + b)[a] * simW[a] ----------
__global__ __launch_bounds__(512, 1) void score_kernel(
    const unsigned short* __restrict__ A,  // lstm_out [BT][256] bf16
    const unsigned short* __restrict__ W,  // mlpwb [256][256] bf16
    const float* __restrict__ mlp_b, const float* __restrict__ sim_W,
    float* __restrict__ score) {
  __shared__ char smem[32768];
  char* As = smem;                       // [128][80B]
  char* Ws = smem + 10240;               // [256][80B]
  float* part = (float*)(smem + 30720);  // [4][128]
  const int tm = blockIdx.x, tid = threadIdx.x;
  const int v = tid >> 6, l = tid & 63;
  const int wm = v >> 2, wn = v & 3;
  const int lr = l & 15, lh = l >> 4;

  f32x4 acc[4][4];
#pragma unroll
  for (int i = 0; i < 4; ++i)
#pragma unroll
    for (int jj = 0; jj < 4; ++jj) acc[i][jj] = f32x4{0.f, 0.f, 0.f, 0.f};

  const unsigned short* Ag = A + (size_t)(tm * 128) * 256;
  s16x8 ra, rw[2];
  {
    int slot = tid, row = slot >> 2, c16 = slot & 3;
    ra = *(const s16x8*)(Ag + (size_t)row * 256 + c16 * 8);
  }
#pragma unroll
  for (int q = 0; q < 2; ++q) {
    int slot = q * 512 + tid, row = slot >> 2, c16 = slot & 3;
    rw[q] = *(const s16x8*)(W + (size_t)row * 256 + c16 * 8);
  }
  for (int kk = 0; kk < 8; ++kk) {
    {
      int slot = tid, row = slot >> 2, c16 = slot & 3;
      *(s16x8*)(As + row * 80 + c16 * 16) = ra;
    }
#pragma unroll
    for (int q = 0; q < 2; ++q) {
      int slot = q * 512 + tid, row = slot >> 2, c16 = slot & 3;
      *(s16x8*)(Ws + row * 80 + c16 * 16) = rw[q];
    }
    __syncthreads();
    if (kk < 7) {
      {
        int slot = tid, row = slot >> 2, c16 = slot & 3;
        ra = *(const s16x8*)(Ag + (size_t)row * 256 + (kk + 1) * 32 + c16 * 8);
      }
#pragma unroll
      for (int q = 0; q < 2; ++q) {
        int slot = q * 512 + tid, row = slot >> 2, c16 = slot & 3;
        rw[q] = *(const s16x8*)(W + (size_t)row * 256 + (kk + 1) * 32 + c16 * 8);
      }
    }
    s16x8 af[4], wfr[4];
#pragma unroll
    for (int mt = 0; mt < 4; ++mt) {
      int r = wm * 64 + mt * 16 + lr;
      af[mt] = *(const s16x8*)(As + r * 80 + lh * 16);
    }
#pragma unroll
    for (int nt = 0; nt < 4; ++nt) {
      int n = wn * 64 + nt * 16 + lr;
      wfr[nt] = *(const s16x8*)(Ws + n * 80 + lh * 16);
    }
#pragma unroll
    for (int mt = 0; mt < 4; ++mt)
#pragma unroll
      for (int nt = 0; nt < 4; ++nt)
        acc[mt][nt] =
            __builtin_amdgcn_mfma_f32_16x16x32_bf16(af[mt], wfr[nt], acc[mt][nt], 0, 0, 0);
    __syncthreads();
  }
  float rowsum[4][4];
#pragma unroll
  for (int mt = 0; mt < 4; ++mt)
#pragma unroll
    for (int vi = 0; vi < 4; ++vi) rowsum[mt][vi] = 0.f;
#pragma unroll
  for (int nt = 0; nt < 4; ++nt) {
    int n = wn * 64 + nt * 16 + lr;
    float mb = mlp_b[n], sw = sim_W[n];
#pragma unroll
    for (int mt = 0; mt < 4; ++mt)
#pragma unroll
      for (int vi = 0; vi < 4; ++vi)
        rowsum[mt][vi] += tanhf_(acc[mt][nt][vi] + mb) * sw;
  }
#pragma unroll
  for (int mt = 0; mt < 4; ++mt)
#pragma unroll
    for (int vi = 0; vi < 4; ++vi) {
#pragma unroll
      for (int off = 1; off < 16; off <<= 1)
        rowsum[mt][vi] += __shfl_xor(rowsum[mt][vi], off, 64);
    }
  if (lr == 0) {
#pragma unroll
    for (int mt = 0; mt < 4; ++mt)
#pragma unroll
      for (int vi = 0; vi < 4; ++vi)
        part[wn * 128 + wm * 64 + mt * 16 + lh * 4 + vi] = rowsum[mt][vi];
  }
  __syncthreads();
  if (tid < 128) {
    float s = part[tid] + part[128 + tid] + part[256 + tid] + part[384 + tid];
    score[tm * 128 + tid] = s;
  }
}

// --- softmax prefix scan -> attn_out bf16 [BT][256] -------------------------
__global__ __launch_bounds__(256, 1) void attn_kernel(
    const float* __restrict__ score, const unsigned short* __restrict__ lstm_out,
    unsigned short* __restrict__ attno) {
  __shared__ float e_s[512];
  __shared__ float rden_s[512];
  const int b = blockIdx.x, tid = threadIdx.x;
  if (tid < 64) {
    float sv[8];
    float m = -1e30f;
    const float* sp = score + b * 512 + tid * 8;
#pragma unroll
    for (int q = 0; q < 8; ++q) {
      sv[q] = sp[q];
      m = fmaxf(m, sv[q]);
    }
#pragma unroll
    for (int off = 1; off < 64; off <<= 1) m = fmaxf(m, __shfl_xor(m, off, 64));
    float loc[8];
    float sum = 0.f;
#pragma unroll
    for (int q = 0; q < 8; ++q) {
      loc[q] = __expf(sv[q] - m);
      sum += loc[q];
    }
    float incl = sum;
#pragma unroll
    for (int d2 = 1; d2 < 64; d2 <<= 1) {
      float o = __shfl_up(incl, d2, 64);
      if (tid >= d2) incl += o;
    }
    float run = incl - sum;  // exclusive prefix of lane sums
#pragma unroll
    for (int q = 0; q < 8; ++q) {
      run += loc[q];
      e_s[tid * 8 + q] = loc[q];
      rden_s[tid * 8 + q] = __builtin_amdgcn_rcpf(run);
    }
  }
  __syncthreads();
  const int d = tid;  // 0..255
  float num = 0.f;
  const unsigned short* hp = lstm_out + (size_t)b * 512 * 256 + d;
  unsigned short* ap = attno + (size_t)b * 512 * 256 + d;
  for (int t = 0; t < 512; ++t) {
    num += e_s[t] * b2f(hp[(size_t)t * 256]);
    ap[(size_t)t * 256] = f2b(num * rden_s[t]);
  }
}

// --- fc GEMM: p = attn_out*(W1hi+W1lo)^T (f32), q = lstm_out*W2^T + b (f32) -
__global__ __launch_bounds__(256, 2) void gemm_fc(
    const unsigned short* __restrict__ A1,    // attno [BT][256]
    const unsigned short* __restrict__ A2,    // lstm  [BT][256]
    const unsigned short* __restrict__ W,     // fcwb [1024][512]
    const unsigned short* __restrict__ W1lo,  // [1024][256]
    const float* __restrict__ bias, float* __restrict__ pout,
    float* __restrict__ qout) {
  __shared__ char smem[20480];
  char* As = smem;
  char* Ws = smem + 10240;
  const int tn = blockIdx.x, tm = blockIdx.y;
  const int tid = threadIdx.x;
  const int v = tid >> 6, l = tid & 63;
  const int wm = v >> 1, wn = v & 1;
  const int lr = l & 15, lh = l >> 4;

  f32x4 acc[4][4];
#pragma unroll
  for (int i = 0; i < 4; ++i)
#pragma unroll
    for (int jj = 0; jj < 4; ++jj) acc[i][jj] = f32x4{0.f, 0.f, 0.f, 0.f};

  auto aload = [&](int kk, int slot) -> s16x8 {
    int row = tm * 128 + (slot >> 2);
    int c = (slot & 3) * 8;
    if (kk < 16) return *(const s16x8*)(A1 + (size_t)row * 256 + (kk & 7) * 32 + c);
    return *(const s16x8*)(A2 + (size_t)row * 256 + ((kk - 16) & 7) * 32 + c);
  };
  auto wload = [&](int kk, int slot) -> s16x8 {
    int row = tn * 128 + (slot >> 2);
    int c = (slot & 3) * 8;
    if (kk < 8) return *(const s16x8*)(W + (size_t)row * 512 + kk * 32 + c);
    if (kk < 16)
      return *(const s16x8*)(W1lo + (size_t)row * 256 + (kk - 8) * 32 + c);
    return *(const s16x8*)(W + (size_t)row * 512 + 256 + (kk - 16) * 32 + c);
  };

  s16x8 ra[2], rw[2];
#pragma unroll
  for (int q = 0; q < 2; ++q) {
    ra[q] = aload(0, q * 256 + tid);
    rw[q] = wload(0, q * 256 + tid);
  }
  for (int kk = 0; kk < 24; ++kk) {
#pragma unroll
    for (int q = 0; q < 2; ++q) {
      int slot = q * 256 + tid, row = slot >> 2, c16 = slot & 3;
      *(s16x8*)(As + row * 80 + c16 * 16) = ra[q];
      *(s16x8*)(Ws + row * 80 + c16 * 16) = rw[q];
    }
    __syncthreads();
    if (kk + 1 < 24) {
#pragma unroll
      for (int q = 0; q < 2; ++q) {
        ra[q] = aload(kk + 1, q * 256 + tid);
        rw[q] = wload(kk + 1, q * 256 + tid);
      }
    }
    s16x8 af[4], wfr[4];
#pragma unroll
    for (int mt = 0; mt < 4; ++mt) {
      int r = wm * 64 + mt * 16 + lr;
      af[mt] = *(const s16x8*)(As + r * 80 + lh * 16);
    }
#pragma unroll
    for (int nt = 0; nt < 4; ++nt) {
      int n = wn * 64 + nt * 16 + lr;
      wfr[nt] = *(const s16x8*)(Ws + n * 80 + lh * 16);
    }
#pragma unroll
    for (int mt = 0; mt < 4; ++mt)
#pragma unroll
      for (int nt = 0; nt < 4; ++nt)
        acc[mt][nt] =
            __builtin_amdgcn_mfma_f32_16x16x32_bf16(af[mt], wfr[nt], acc[mt][nt], 0, 0, 0);
    __syncthreads();
    if (kk == 15) {  // write p, reset accumulators for q phase
#pragma unroll
      for (int mt = 0; mt < 4; ++mt) {
#pragma unroll
        for (int nt = 0; nt < 4; ++nt) {
          int col = tn * 128 + wn * 64 + nt * 16 + lr;
#pragma unroll
          for (int vi = 0; vi < 4; ++vi) {
            int row = tm * 128 + wm * 64 + mt * 16 + lh * 4 + vi;
            pout[(size_t)row * 1024 + col] = acc[mt][nt][vi];
          }
          acc[mt][nt] = f32x4{0.f, 0.f, 0.f, 0.f};
        }
      }
    }
  }
#pragma unroll
  for (int mt = 0; mt < 4; ++mt) {
#pragma unroll
    for (int nt = 0; nt < 4; ++nt) {
      int col = tn * 128 + wn * 64 + nt * 16 + lr;
      float bv = bias[col];
#pragma unroll
      for (int vi = 0; vi < 4; ++vi) {
        int row = tm * 128 + wm * 64 + mt * 16 + lh * 4 + vi;
        qout[(size_t)row * 1024 + col] = acc[mt][nt][vi] + bv;
      }
    }
  }
}

// --- exact f32 prefix over p + sigmoid: out[t] = sig(q[t] + sum_{t'<t} p) ---
__global__ __launch_bounds__(256, 1) void scan_pq(const float* __restrict__ p,
                                                  float* __restrict__ q) {
  const int c = blockIdx.x * 256 + threadIdx.x;  // 0..1023
  const int b = blockIdx.y;
  const size_t base = ((size_t)b * 512) * 1024 + c;
  float cum = 0.f;
#pragma unroll 4
  for (int t = 0; t < 512; ++t) {
    size_t idx = base + (size_t)t * 1024;
    float pv = p[idx];
    float qv = q[idx];
    q[idx] = sigf(qv + cum);
    cum += pv;
  }
}

extern "C" void kernel_launch(void* const* d_in, const int* in_sizes, int n_in,
                              void* d_out, int out_size, void* d_ws, size_t ws_size,
                              hipStream_t stream) {
  const int* cseq = (const int*)d_in[0];
  const int* kseq = (const int*)d_in[1];
  const float* embC = (const float*)d_in[2];
  const float* embR = (const float*)d_in[3];
  const float* W_ih = (const float*)d_in[4];
  const float* W_hh = (const float*)d_in[5];
  const float* b_ih = (const float*)d_in[6];
  const float* b_hh = (const float*)d_in[7];
  const float* mlp_W = (const float*)d_in[8];
  const float* mlp_b = (const float*)d_in[9];
  const float* sim_W = (const float*)d_in[10];
  const float* fc_W = (const float*)d_in[11];
  const float* fc_b = (const float*)d_in[12];
  char* ws = (char*)d_ws;

  unsigned short* inter  = (unsigned short*)(ws + 0);           // 33,554,432
  unsigned short* wihb   = (unsigned short*)(ws + 33554432);    // 1,048,576
  unsigned short* fcwb   = (unsigned short*)(ws + 34603008);    // 1,048,576
  unsigned short* mlpwb  = (unsigned short*)(ws + 35651584);    // 131,072
  unsigned short* fcw1lo = (unsigned short*)(ws + 35782656);    // 524,288
  float* xg              = (float*)(ws + 36306944);             // 134,217,728
  float* pbuf            = xg;                                  // reuse after LSTM
  unsigned short* lstm   = (unsigned short*)(ws + 170524672);   // 16,777,216
  unsigned short* attno  = (unsigned short*)(ws + 187301888);   // 16,777,216
  unsigned short* hbuf_hi= (unsigned short*)(ws + 204079104);   // 65,536
  unsigned short* hbuf_lo= (unsigned short*)(ws + 204144640);   // 65,536
  int* flags             = (int*)(ws + 204210176);              // 4,096
  float* score           = (float*)(ws + 204214272);            // 131,072

  float* qbuf = (float*)d_out;  // q staged in-place, finalized by scan_pq

  prep_kernel<<<dim3(4352), dim3(256), 0, stream>>>(W_ih, fc_W, mlp_W, wihb,
                                                    fcwb, mlpwb, fcw1lo, flags);
  interact_kernel<<<dim3(8192), dim3(256), 0, stream>>>(cseq, kseq, embC, embR,
                                                        inter);
  gemm_xg<<<dim3(8, 256), dim3(256), 0, stream>>>(inter, wihb, b_ih, b_hh, xg);
  lstm_kernel<<<dim3(16), dim3(256), 0, stream>>>(W_hh, xg, hbuf_hi, hbuf_lo,
                                                  lstm, flags);
  score_kernel<<<dim3(256), dim3(512), 0, stream>>>(lstm, mlpwb, mlp_b, sim_W,
                                                    score);
  attn_kernel<<<dim3(64), dim3(256), 0, stream>>>(score, lstm, attno);
  gemm_fc<<<dim3(8, 256), dim3(256), 0, stream>>>(attno, lstm, fcwb, fcw1lo,
                                                  fc_b, pbuf, qbuf);
  scan_pq<<<dim3(4, 64), dim3(256), 0, stream>>>(pbuf, qbuf);
}

// Round 6
// 3448.333 us; speedup vs baseline: 1.1393x; 1.1393x over previous
//
#include <hip/hip_runtime.h>

// ---------------------------------------------------------------------------
// ATKT forward on MI355X.
// prep -> interaction embed -> xg GEMM (bf16 MFMA, f32 out) ->
// LSTM: 4 independent teams of 4 WGs (one per 16-batch group), W_hh in VGPRs.
//   Team protocol chosen at runtime from XCC_IDs: all-same-XCD -> sc0 L2-local
//   sync; else -> agent-scope atomics (round-3 proven protocol).
// -> score GEMM -> softmax prefix scan -> fc GEMM (p,q) -> f32 prefix+sigmoid.
// ---------------------------------------------------------------------------

typedef __attribute__((ext_vector_type(4))) float f32x4;
typedef __attribute__((ext_vector_type(8))) short s16x8;
typedef __attribute__((ext_vector_type(4))) short s16x4;

__device__ __forceinline__ unsigned short f2b(float f) {
  unsigned u = __float_as_uint(f);
  u += 0x7FFFu + ((u >> 16) & 1u);
  return (unsigned short)(u >> 16);
}
__device__ __forceinline__ float b2f(unsigned short s) {
  return __uint_as_float(((unsigned)s) << 16);
}
__device__ __forceinline__ float sigf(float x) {
  return __builtin_amdgcn_rcpf(1.f + __expf(-x));
}
__device__ __forceinline__ float tanhf_(float x) {
  return 1.f - 2.f * __builtin_amdgcn_rcpf(1.f + __expf(2.f * x));
}

// --- prep: bf16 conversions + fc_W1 lo-residual + zero LSTM flags/ids -------
__global__ void prep_kernel(const float* __restrict__ W_ih,
                            const float* __restrict__ fc_W,
                            const float* __restrict__ mlp_W,
                            unsigned short* __restrict__ wihb,
                            unsigned short* __restrict__ fcwb,
                            unsigned short* __restrict__ mlpwb,
                            unsigned short* __restrict__ fcw1lo,
                            int* __restrict__ flags) {
  int i = blockIdx.x * 256 + threadIdx.x;
  if (i < 524288) {
    wihb[i] = f2b(W_ih[i]);
  } else if (i < 1048576) {
    int j = i - 524288;
    float w = fc_W[j];
    unsigned short h = f2b(w);
    fcwb[j] = h;
    int col = j & 511;
    if (col < 256) fcw1lo[(size_t)(j >> 9) * 256 + col] = f2b(w - b2f(h));
  } else if (i < 1114112) {
    mlpwb[i - 1048576] = f2b(mlp_W[i - 1048576]);
  }
  if (i < 1536) flags[i] = 0;  // wave flags (0..1023) + xcd ids (1024..1279)
}

// --- interaction embedding: [BT][512] bf16 ----------------------------------
__global__ void interact_kernel(const int* __restrict__ cseq,
                                const int* __restrict__ kseq,
                                const float* __restrict__ embC,
                                const float* __restrict__ embR,
                                unsigned short* __restrict__ inter) {
  int bt = blockIdx.x * 4 + (threadIdx.x >> 6);
  int l = threadIdx.x & 63;
  int c = cseq[bt], k = kseq[bt];
  const float* h1 = k ? (embC + (size_t)c * 256) : embR;          // first half
  const float* h2 = k ? (embR + 256) : (embC + (size_t)c * 256);  // second half
  int seg = l * 8;
  const float* src = (seg < 256) ? (h1 + seg) : (h2 + (seg - 256));
  s16x8 vv;
#pragma unroll
  for (int q = 0; q < 8; ++q) vv[q] = (short)f2b(src[q]);
  *(s16x8*)(inter + (size_t)bt * 512 + seg) = vv;
}

// --- xg GEMM: xg[M][1024](f32) = A[M][512](bf16) x W[1024][512]^T + b1+b2 ---
__global__ __launch_bounds__(256, 2) void gemm_xg(
    const unsigned short* __restrict__ A, const unsigned short* __restrict__ W,
    const float* __restrict__ bias1, const float* __restrict__ bias2,
    float* __restrict__ outp) {
  constexpr int KW = 512;
  __shared__ char smem[20480];
  char* As = smem;          // [128][80B]
  char* Ws = smem + 10240;  // [128][80B]
  const int tn = blockIdx.x, tm = blockIdx.y;
  const int tid = threadIdx.x;
  const int v = tid >> 6, l = tid & 63;
  const int wm = v >> 1, wn = v & 1;
  const int lr = l & 15, lh = l >> 4;

  f32x4 acc[4][4];
#pragma unroll
  for (int i = 0; i < 4; ++i)
#pragma unroll
    for (int jj = 0; jj < 4; ++jj) acc[i][jj] = f32x4{0.f, 0.f, 0.f, 0.f};

  const unsigned short* Ag = A + (size_t)(tm * 128) * KW;
  const unsigned short* Wg = W + (size_t)(tn * 128) * KW;

  s16x8 ra[2], rw[2];
#pragma unroll
  for (int q = 0; q < 2; ++q) {
    int slot = q * 256 + tid, row = slot >> 2, c16 = slot & 3;
    ra[q] = *(const s16x8*)(Ag + (size_t)row * KW + c16 * 8);
    rw[q] = *(const s16x8*)(Wg + (size_t)row * KW + c16 * 8);
  }
  for (int kk = 0; kk < KW / 32; ++kk) {
#pragma unroll
    for (int q = 0; q < 2; ++q) {
      int slot = q * 256 + tid, row = slot >> 2, c16 = slot & 3;
      *(s16x8*)(As + row * 80 + c16 * 16) = ra[q];
      *(s16x8*)(Ws + row * 80 + c16 * 16) = rw[q];
    }
    __syncthreads();
    if (kk + 1 < KW / 32) {
#pragma unroll
      for (int q = 0; q < 2; ++q) {
        int slot = q * 256 + tid, row = slot >> 2, c16 = slot & 3;
        ra[q] = *(const s16x8*)(Ag + (size_t)row * KW + (kk + 1) * 32 + c16 * 8);
        rw[q] = *(const s16x8*)(Wg + (size_t)row * KW + (kk + 1) * 32 + c16 * 8);
      }
    }
    s16x8 af[4], wf[4];
#pragma unroll
    for (int mt = 0; mt < 4; ++mt) {
      int r = wm * 64 + mt * 16 + lr;
      af[mt] = *(const s16x8*)(As + r * 80 + lh * 16);
    }
#pragma unroll
    for (int nt = 0; nt < 4; ++nt) {
      int n = wn * 64 + nt * 16 + lr;
      wf[nt] = *(const s16x8*)(Ws + n * 80 + lh * 16);
    }
#pragma unroll
    for (int mt = 0; mt < 4; ++mt)
#pragma unroll
      for (int nt = 0; nt < 4; ++nt)
        acc[mt][nt] =
            __builtin_amdgcn_mfma_f32_16x16x32_bf16(af[mt], wf[nt], acc[mt][nt], 0, 0, 0);
    __syncthreads();
  }
#pragma unroll
  for (int mt = 0; mt < 4; ++mt) {
#pragma unroll
    for (int nt = 0; nt < 4; ++nt) {
      int col = tn * 128 + wn * 64 + nt * 16 + lr;
      float bv = bias1[col] + bias2[col];
#pragma unroll
      for (int vi = 0; vi < 4; ++vi) {
        int row = tm * 128 + wm * 64 + mt * 16 + lh * 4 + vi;
        outp[(size_t)row * 1024 + col] = acc[mt][nt][vi] + bv;
      }
    }
  }
}

// --- LSTM: 4 independent 4-WG teams; per-team sc0 (XCD-local) or agent sync -
__global__ __launch_bounds__(256, 1) void lstm_kernel(
    const float* __restrict__ W_hh, const float* __restrict__ xg,
    unsigned short* __restrict__ hbuf_hi, unsigned short* __restrict__ hbuf_lo,
    unsigned short* __restrict__ lstm_out, int* __restrict__ flags) {
  const int blk = blockIdx.x;
  const int gg = blk & 7;
  if (gg >= 4) return;       // 16 worker WGs; rest exit
  const int g = gg;          // batch-group (team id)
  const int j = blk >> 3;    // d-slice within team
  const int tid = threadIdx.x;
  const int v = tid >> 6, l = tid & 63;
  const int lr = l & 15, lh = l >> 4;

  // ---- one-time team XCD-id exchange (agent scope, bounded: all resident) --
  __shared__ int sh_fast;
  if (tid == 0) {
    int xcd;
    asm volatile("s_getreg_b32 %0, hwreg(HW_REG_XCC_ID)" : "=s"(xcd));
    xcd &= 15;
    __hip_atomic_store(flags + 1024 + (g * 4 + j) * 16, xcd + 1,
                       __ATOMIC_RELEASE, __HIP_MEMORY_SCOPE_AGENT);
    int ok = 1, id0 = 0;
    for (int s2 = 0; s2 < 4; ++s2) {
      int v2;
      do {
        v2 = __hip_atomic_load(flags + 1024 + (g * 4 + s2) * 16,
                               __ATOMIC_ACQUIRE, __HIP_MEMORY_SCOPE_AGENT);
        if (v2 == 0) __builtin_amdgcn_s_sleep(1);
      } while (v2 == 0);
      if (s2 == 0) id0 = v2;
      else if (v2 != id0) ok = 0;
    }
    sh_fast = ok;
  }
  __syncthreads();
  const bool fast = (sh_fast != 0);

  // W_hh slice as MFMA A-fragments in registers (bf16).
  s16x8 wf[4][8];
#pragma unroll
  for (int gt = 0; gt < 4; ++gt) {
    const float* wr = W_hh + (size_t)(gt * 256 + j * 64 + v * 16 + lr) * 256;
#pragma unroll
    for (int kc = 0; kc < 8; ++kc) {
      const float* p = wr + kc * 32 + lh * 8;
      s16x8 t;
#pragma unroll
      for (int q = 0; q < 8; ++q) t[q] = (short)f2b(p[q]);
      wf[gt][kc] = t;
    }
  }
  const int bcol = g * 16 + lr;                // batch (D-layout col = l&15)
  const int dbase = j * 64 + v * 16 + lh * 4;  // D-layout row base (+vi)
  const float* xgp = xg + (size_t)bcol * 512 * 1024 + dbase;
  float cst[4] = {0.f, 0.f, 0.f, 0.f};
  int* myflag = flags + (g * 16 + j * 4 + v) * 16;
  int* fp = flags + (g * 16 + (l & 15)) * 16;

  f32x4 xpre[4];
#pragma unroll
  for (int gt = 0; gt < 4; ++gt) xpre[gt] = *(const f32x4*)(xgp + gt * 256);

  if (fast) {
    // ---- FAST: all 4 WGs on one XCD; sc0 ops through the shared L2 ----
    int slowpoll = 0;
    for (int t = 0; t < 512; ++t) {
      f32x4 acc[4];
#pragma unroll
      for (int gt = 0; gt < 4; ++gt) acc[gt] = xpre[gt];
      if (t > 0) {
        if (!slowpoll) {
          int spins = 0;
          while (true) {
            int fv;
            asm volatile(
                "global_load_dword %0, %1, off sc0\n\ts_waitcnt vmcnt(0)"
                : "=v"(fv)
                : "v"(fp)
                : "memory");
            if (__all(fv >= t)) break;
            if (++spins > 4096) { slowpoll = 1; break; }
          }
        }
        if (slowpoll) {  // same-XCD: acquire still observes sc0 stores
          while (true) {
            int fv = __hip_atomic_load(fp, __ATOMIC_ACQUIRE,
                                       __HIP_MEMORY_SCOPE_AGENT);
            if (__all(fv >= t)) break;
            __builtin_amdgcn_s_sleep(1);
          }
        }
        __builtin_amdgcn_sched_barrier(0);
        size_t hb_off = ((size_t)(((t - 1) & 1) * 4 + g) * 16 + lr) * 256;
        s16x8 hf_hi[8], hf_lo[8];
#pragma unroll
        for (int kc = 0; kc < 8; ++kc) {
          asm volatile("global_load_dwordx4 %0, %1, off sc0"
                       : "=v"(hf_hi[kc])
                       : "v"(hbuf_hi + hb_off + kc * 32 + lh * 8));
          asm volatile("global_load_dwordx4 %0, %1, off sc0"
                       : "=v"(hf_lo[kc])
                       : "v"(hbuf_lo + hb_off + kc * 32 + lh * 8));
        }
        {  // issue next xg; drains under MFMA (vmcnt(4) leaves these 4 live)
          const float* xa = xgp + (size_t)((t < 511) ? t + 1 : t) * 1024;
#pragma unroll
          for (int gt = 0; gt < 4; ++gt)
            asm volatile("global_load_dwordx4 %0, %1, off"
                         : "=v"(xpre[gt])
                         : "v"(xa + gt * 256));
        }
        asm volatile("s_waitcnt vmcnt(4)" ::: "memory");
        __builtin_amdgcn_sched_barrier(0);
#pragma unroll
        for (int gt = 0; gt < 4; ++gt) {
#pragma unroll
          for (int kc = 0; kc < 8; ++kc)
            acc[gt] = __builtin_amdgcn_mfma_f32_16x16x32_bf16(
                wf[gt][kc], hf_hi[kc], acc[gt], 0, 0, 0);
#pragma unroll
          for (int kc = 0; kc < 8; ++kc)
            acc[gt] = __builtin_amdgcn_mfma_f32_16x16x32_bf16(
                wf[gt][kc], hf_lo[kc], acc[gt], 0, 0, 0);
        }
      } else {
        const float* xa = xgp + 1024;
#pragma unroll
        for (int gt = 0; gt < 4; ++gt)
          asm volatile("global_load_dwordx4 %0, %1, off"
                       : "=v"(xpre[gt])
                       : "v"(xa + gt * 256));
      }
      s16x4 hhi, hlo;
#pragma unroll
      for (int vi = 0; vi < 4; ++vi) {
        float ig = sigf(acc[0][vi]);
        float fg = sigf(acc[1][vi]);
        float gb = tanhf_(acc[2][vi]);
        float og = sigf(acc[3][vi]);
        cst[vi] = fg * cst[vi] + ig * gb;
        float hv = og * tanhf_(cst[vi]);
        unsigned short hb = f2b(hv);
        hhi[vi] = (short)hb;
        hlo[vi] = (short)f2b(hv - b2f(hb));
      }
      size_t wo = ((size_t)((t & 1) * 4 + g) * 16 + lr) * 256 + dbase;
      asm volatile("global_store_dwordx2 %0, %1, off sc0" ::"v"(hbuf_hi + wo),
                   "v"(hhi)
                   : "memory");
      asm volatile("global_store_dwordx2 %0, %1, off sc0" ::"v"(hbuf_lo + wo),
                   "v"(hlo)
                   : "memory");
      *(s16x4*)(lstm_out + ((size_t)bcol * 512 + t) * 256 + dbase) = hhi;
      asm volatile("s_waitcnt vmcnt(0)" ::: "memory");
      if (l == 0) {
        int tv = t + 1;
        asm volatile("global_store_dword %0, %1, off sc0" ::"v"(myflag),
                     "v"(tv)
                     : "memory");
      }
      __builtin_amdgcn_sched_barrier(0);
    }
  } else {
    // ---- SLOW: round-3 proven agent-scope protocol ----
    for (int t = 0; t < 512; ++t) {
      f32x4 acc[4];
#pragma unroll
      for (int gt = 0; gt < 4; ++gt) acc[gt] = xpre[gt];
      if (t > 0) {
        while (true) {
          int fv =
              __hip_atomic_load(fp, __ATOMIC_ACQUIRE, __HIP_MEMORY_SCOPE_AGENT);
          if (__all(fv >= t)) break;
          __builtin_amdgcn_s_sleep(1);
        }
        size_t hb_off = ((size_t)(((t - 1) & 1) * 4 + g) * 16 + lr) * 256;
        s16x8 hf_hi[8], hf_lo[8];
#pragma unroll
        for (int kc = 0; kc < 8; ++kc) {
          hf_hi[kc] = *(const s16x8*)(hbuf_hi + hb_off + kc * 32 + lh * 8);
          hf_lo[kc] = *(const s16x8*)(hbuf_lo + hb_off + kc * 32 + lh * 8);
        }
#pragma unroll
        for (int gt = 0; gt < 4; ++gt) {
#pragma unroll
          for (int kc = 0; kc < 8; ++kc)
            acc[gt] = __builtin_amdgcn_mfma_f32_16x16x32_bf16(
                wf[gt][kc], hf_hi[kc], acc[gt], 0, 0, 0);
#pragma unroll
          for (int kc = 0; kc < 8; ++kc)
            acc[gt] = __builtin_amdgcn_mfma_f32_16x16x32_bf16(
                wf[gt][kc], hf_lo[kc], acc[gt], 0, 0, 0);
        }
      }
      if (t < 511) {
#pragma unroll
        for (int gt = 0; gt < 4; ++gt)
          xpre[gt] = *(const f32x4*)(xgp + (size_t)(t + 1) * 1024 + gt * 256);
      }
      s16x4 hhi, hlo;
#pragma unroll
      for (int vi = 0; vi < 4; ++vi) {
        float ig = sigf(acc[0][vi]);
        float fg = sigf(acc[1][vi]);
        float gb = tanhf_(acc[2][vi]);
        float og = sigf(acc[3][vi]);
        cst[vi] = fg * cst[vi] + ig * gb;
        float hv = og * tanhf_(cst[vi]);
        unsigned short hb = f2b(hv);
        hhi[vi] = (short)hb;
        hlo[vi] = (short)f2b(hv - b2f(hb));
      }
      size_t wo = ((size_t)((t & 1) * 4 + g) * 16 + lr) * 256 + dbase;
      *(s16x4*)(hbuf_hi + wo) = hhi;
      *(s16x4*)(hbuf_lo + wo) = hlo;
      *(s16x4*)(lstm_out + ((size_t)bcol * 512 + t) * 256 + dbase) = hhi;
      if (l == 0)
        __hip_atomic_store(myflag, t + 1, __ATOMIC_RELEASE,
                           __HIP_MEMORY_SCOPE_AGENT);
    }
  }
}

// --- score GEMM: score[bt] = sum_a tanh(H mlpW^T + b)[a] * simW[a] ----------
__global__ __launch_bounds__(512, 1) void score_kernel(
    const unsigned short* __restrict__ A,  // lstm_out [BT][256] bf16
    const unsigned short* __restrict__ W,  // mlpwb [256][256] bf16
    const float* __restrict__ mlp_b, const float* __restrict__ sim_W,
    float* __restrict__ score) {
  __shared__ char smem[32768];
  char* As = smem;                       // [128][80B]
  char* Ws = smem + 10240;               // [256][80B]
  float* part = (float*)(smem + 30720);  // [4][128]
  const int tm = blockIdx.x, tid = threadIdx.x;
  const int v = tid >> 6, l = tid & 63;
  const int wm = v >> 2, wn = v & 3;
  const int lr = l & 15, lh = l >> 4;

  f32x4 acc[4][4];
#pragma unroll
  for (int i = 0; i < 4; ++i)
#pragma unroll
    for (int jj = 0; jj < 4; ++jj) acc[i][jj] = f32x4{0.f, 0.f, 0.f, 0.f};

  const unsigned short* Ag = A + (size_t)(tm * 128) * 256;
  s16x8 ra, rw[2];
  {
    int slot = tid, row = slot >> 2, c16 = slot & 3;
    ra = *(const s16x8*)(Ag + (size_t)row * 256 + c16 * 8);
  }
#pragma unroll
  for (int q = 0; q < 2; ++q) {
    int slot = q * 512 + tid, row = slot >> 2, c16 = slot & 3;
    rw[q] = *(const s16x8*)(W + (size_t)row * 256 + c16 * 8);
  }
  for (int kk = 0; kk < 8; ++kk) {
    {
      int slot = tid, row = slot >> 2, c16 = slot & 3;
      *(s16x8*)(As + row * 80 + c16 * 16) = ra;
    }
#pragma unroll
    for (int q = 0; q < 2; ++q) {
      int slot = q * 512 + tid, row = slot >> 2, c16 = slot & 3;
      *(s16x8*)(Ws + row * 80 + c16 * 16) = rw[q];
    }
    __syncthreads();
    if (kk < 7) {
      {
        int slot = tid, row = slot >> 2, c16 = slot & 3;
        ra = *(const s16x8*)(Ag + (size_t)row * 256 + (kk + 1) * 32 + c16 * 8);
      }
#pragma unroll
      for (int q = 0; q < 2; ++q) {
        int slot = q * 512 + tid, row = slot >> 2, c16 = slot & 3;
        rw[q] = *(const s16x8*)(W + (size_t)row * 256 + (kk + 1) * 32 + c16 * 8);
      }
    }
    s16x8 af[4], wfr[4];
#pragma unroll
    for (int mt = 0; mt < 4; ++mt) {
      int r = wm * 64 + mt * 16 + lr;
      af[mt] = *(const s16x8*)(As + r * 80 + lh * 16);
    }
#pragma unroll
    for (int nt = 0; nt < 4; ++nt) {
      int n = wn * 64 + nt * 16 + lr;
      wfr[nt] = *(const s16x8*)(Ws + n * 80 + lh * 16);
    }
#pragma unroll
    for (int mt = 0; mt < 4; ++mt)
#pragma unroll
      for (int nt = 0; nt < 4; ++nt)
        acc[mt][nt] =
            __builtin_amdgcn_mfma_f32_16x16x32_bf16(af[mt], wfr[nt], acc[mt][nt], 0, 0, 0);
    __syncthreads();
  }
  float rowsum[4][4];
#pragma unroll
  for (int mt = 0; mt < 4; ++mt)
#pragma unroll
    for (int vi = 0; vi < 4; ++vi) rowsum[mt][vi] = 0.f;
#pragma unroll
  for (int nt = 0; nt < 4; ++nt) {
    int n = wn * 64 + nt * 16 + lr;
    float mb = mlp_b[n], sw = sim_W[n];
#pragma unroll
    for (int mt = 0; mt < 4; ++mt)
#pragma unroll
      for (int vi = 0; vi < 4; ++vi)
        rowsum[mt][vi] += tanhf_(acc[mt][nt][vi] + mb) * sw;
  }
#pragma unroll
  for (int mt = 0; mt < 4; ++mt)
#pragma unroll
    for (int vi = 0; vi < 4; ++vi) {
#pragma unroll
      for (int off = 1; off < 16; off <<= 1)
        rowsum[mt][vi] += __shfl_xor(rowsum[mt][vi], off, 64);
    }
  if (lr == 0) {
#pragma unroll
    for (int mt = 0; mt < 4; ++mt)
#pragma unroll
      for (int vi = 0; vi < 4; ++vi)
        part[wn * 128 + wm * 64 + mt * 16 + lh * 4 + vi] = rowsum[mt][vi];
  }
  __syncthreads();
  if (tid < 128) {
    float s = part[tid] + part[128 + tid] + part[256 + tid] + part[384 + tid];
    score[tm * 128 + tid] = s;
  }
}

// --- softmax prefix scan -> attn_out bf16 [BT][256] -------------------------
__global__ __launch_bounds__(256, 1) void attn_kernel(
    const float* __restrict__ score, const unsigned short* __restrict__ lstm_out,
    unsigned short* __restrict__ attno) {
  __shared__ float e_s[512];
  __shared__ float rden_s[512];
  const int b = blockIdx.x, tid = threadIdx.x;
  if (tid < 64) {
    float sv[8];
    float m = -1e30f;
    const float* sp = score + b * 512 + tid * 8;
#pragma unroll
    for (int q = 0; q < 8; ++q) {
      sv[q] = sp[q];
      m = fmaxf(m, sv[q]);
    }
#pragma unroll
    for (int off = 1; off < 64; off <<= 1) m = fmaxf(m, __shfl_xor(m, off, 64));
    float loc[8];
    float sum = 0.f;
#pragma unroll
    for (int q = 0; q < 8; ++q) {
      loc[q] = __expf(sv[q] - m);
      sum += loc[q];
    }
    float incl = sum;
#pragma unroll
    for (int d2 = 1; d2 < 64; d2 <<= 1) {
      float o = __shfl_up(incl, d2, 64);
      if (tid >= d2) incl += o;
    }
    float run = incl - sum;  // exclusive prefix of lane sums
#pragma unroll
    for (int q = 0; q < 8; ++q) {
      run += loc[q];
      e_s[tid * 8 + q] = loc[q];
      rden_s[tid * 8 + q] = __builtin_amdgcn_rcpf(run);
    }
  }
  __syncthreads();
  const int d = tid;  // 0..255
  float num = 0.f;
  const unsigned short* hp = lstm_out + (size_t)b * 512 * 256 + d;
  unsigned short* ap = attno + (size_t)b * 512 * 256 + d;
  for (int t = 0; t < 512; ++t) {
    num += e_s[t] * b2f(hp[(size_t)t * 256]);
    ap[(size_t)t * 256] = f2b(num * rden_s[t]);
  }
}

// --- fc GEMM: p = attn_out*(W1hi+W1lo)^T (f32), q = lstm_out*W2^T + b (f32) -
__global__ __launch_bounds__(256, 2) void gemm_fc(
    const unsigned short* __restrict__ A1,    // attno [BT][256]
    const unsigned short* __restrict__ A2,    // lstm  [BT][256]
    const unsigned short* __restrict__ W,     // fcwb [1024][512]
    const unsigned short* __restrict__ W1lo,  // [1024][256]
    const float* __restrict__ bias, float* __restrict__ pout,
    float* __restrict__ qout) {
  __shared__ char smem[20480];
  char* As = smem;
  char* Ws = smem + 10240;
  const int tn = blockIdx.x, tm = blockIdx.y;
  const int tid = threadIdx.x;
  const int v = tid >> 6, l = tid & 63;
  const int wm = v >> 1, wn = v & 1;
  const int lr = l & 15, lh = l >> 4;

  f32x4 acc[4][4];
#pragma unroll
  for (int i = 0; i < 4; ++i)
#pragma unroll
    for (int jj = 0; jj < 4; ++jj) acc[i][jj] = f32x4{0.f, 0.f, 0.f, 0.f};

  auto aload = [&](int kk, int slot) -> s16x8 {
    int row = tm * 128 + (slot >> 2);
    int c = (slot & 3) * 8;
    if (kk < 16) return *(const s16x8*)(A1 + (size_t)row * 256 + (kk & 7) * 32 + c);
    return *(const s16x8*)(A2 + (size_t)row * 256 + ((kk - 16) & 7) * 32 + c);
  };
  auto wload = [&](int kk, int slot) -> s16x8 {
    int row = tn * 128 + (slot >> 2);
    int c = (slot & 3) * 8;
    if (kk < 8) return *(const s16x8*)(W + (size_t)row * 512 + kk * 32 + c);
    if (kk < 16)
      return *(const s16x8*)(W1lo + (size_t)row * 256 + (kk - 8) * 32 + c);
    return *(const s16x8*)(W + (size_t)row * 512 + 256 + (kk - 16) * 32 + c);
  };

  s16x8 ra[2], rw[2];
#pragma unroll
  for (int q = 0; q < 2; ++q) {
    ra[q] = aload(0, q * 256 + tid);
    rw[q] = wload(0, q * 256 + tid);
  }
  for (int kk = 0; kk < 24; ++kk) {
#pragma unroll
    for (int q = 0; q < 2; ++q) {
      int slot = q * 256 + tid, row = slot >> 2, c16 = slot & 3;
      *(s16x8*)(As + row * 80 + c16 * 16) = ra[q];
      *(s16x8*)(Ws + row * 80 + c16 * 16) = rw[q];
    }
    __syncthreads();
    if (kk + 1 < 24) {
#pragma unroll
      for (int q = 0; q < 2; ++q) {
        ra[q] = aload(kk + 1, q * 256 + tid);
        rw[q] = wload(kk + 1, q * 256 + tid);
      }
    }
    s16x8 af[4], wfr[4];
#pragma unroll
    for (int mt = 0; mt < 4; ++mt) {
      int r = wm * 64 + mt * 16 + lr;
      af[mt] = *(const s16x8*)(As + r * 80 + lh * 16);
    }
#pragma unroll
    for (int nt = 0; nt < 4; ++nt) {
      int n = wn * 64 + nt * 16 + lr;
      wfr[nt] = *(const s16x8*)(Ws + n * 80 + lh * 16);
    }
#pragma unroll
    for (int mt = 0; mt < 4; ++mt)
#pragma unroll
      for (int nt = 0; nt < 4; ++nt)
        acc[mt][nt] =
            __builtin_amdgcn_mfma_f32_16x16x32_bf16(af[mt], wfr[nt], acc[mt][nt], 0, 0, 0);
    __syncthreads();
    if (kk == 15) {  // write p, reset accumulators for q phase
#pragma unroll
      for (int mt = 0; mt < 4; ++mt) {
#pragma unroll
        for (int nt = 0; nt < 4; ++nt) {
          int col = tn * 128 + wn * 64 + nt * 16 + lr;
#pragma unroll
          for (int vi = 0; vi < 4; ++vi) {
            int row = tm * 128 + wm * 64 + mt * 16 + lh * 4 + vi;
            pout[(size_t)row * 1024 + col] = acc[mt][nt][vi];
          }
          acc[mt][nt] = f32x4{0.f, 0.f, 0.f, 0.f};
        }
      }
    }
  }
#pragma unroll
  for (int mt = 0; mt < 4; ++mt) {
#pragma unroll
    for (int nt = 0; nt < 4; ++nt) {
      int col = tn * 128 + wn * 64 + nt * 16 + lr;
      float bv = bias[col];
#pragma unroll
      for (int vi = 0; vi < 4; ++vi) {
        int row = tm * 128 + wm * 64 + mt * 16 + lh * 4 + vi;
        qout[(size_t)row * 1024 + col] = acc[mt][nt][vi] + bv;
      }
    }
  }
}

// --- exact f32 prefix over p + sigmoid: out[t] = sig(q[t] + sum_{t'<t} p) ---
__global__ __launch_bounds__(256, 1) void scan_pq(const float* __restrict__ p,
                                                  float* __restrict__ q) {
  const int c = blockIdx.x * 256 + threadIdx.x;  // 0..1023
  const int b = blockIdx.y;
  const size_t base = ((size_t)b * 512) * 1024 + c;
  float cum = 0.f;
#pragma unroll 4
  for (int t = 0; t < 512; ++t) {
    size_t idx = base + (size_t)t * 1024;
    float pv = p[idx];
    float qv = q[idx];
    q[idx] = sigf(qv + cum);
    cum += pv;
  }
}

extern "C" void kernel_launch(void* const* d_in, const int* in_sizes, int n_in,
                              void* d_out, int out_size, void* d_ws, size_t ws_size,
                              hipStream_t stream) {
  const int* cseq = (const int*)d_in[0];
  const int* kseq = (const int*)d_in[1];
  const float* embC = (const float*)d_in[2];
  const float* embR = (const float*)d_in[3];
  const float* W_ih = (const float*)d_in[4];
  const float* W_hh = (const float*)d_in[5];
  const float* b_ih = (const float*)d_in[6];
  const float* b_hh = (const float*)d_in[7];
  const float* mlp_W = (const float*)d_in[8];
  const float* mlp_b = (const float*)d_in[9];
  const float* sim_W = (const float*)d_in[10];
  const float* fc_W = (const float*)d_in[11];
  const float* fc_b = (const float*)d_in[12];
  char* ws = (char*)d_ws;

  unsigned short* inter  = (unsigned short*)(ws + 0);           // 33,554,432
  unsigned short* wihb   = (unsigned short*)(ws + 33554432);    // 1,048,576
  unsigned short* fcwb   = (unsigned short*)(ws + 34603008);    // 1,048,576
  unsigned short* mlpwb  = (unsigned short*)(ws + 35651584);    // 131,072
  unsigned short* fcw1lo = (unsigned short*)(ws + 35782656);    // 524,288
  float* xg              = (float*)(ws + 36306944);             // 134,217,728
  float* pbuf            = xg;                                  // reuse after LSTM
  unsigned short* lstm   = (unsigned short*)(ws + 170524672);   // 16,777,216
  unsigned short* attno  = (unsigned short*)(ws + 187301888);   // 16,777,216
  unsigned short* hbuf_hi= (unsigned short*)(ws + 204079104);   // 65,536
  unsigned short* hbuf_lo= (unsigned short*)(ws + 204144640);   // 65,536
  int* flags             = (int*)(ws + 204210176);              // 8,192
  float* score           = (float*)(ws + 204218368);            // 131,072

  float* qbuf = (float*)d_out;  // q staged in-place, finalized by scan_pq

  prep_kernel<<<dim3(4352), dim3(256), 0, stream>>>(W_ih, fc_W, mlp_W, wihb,
                                                    fcwb, mlpwb, fcw1lo, flags);
  interact_kernel<<<dim3(8192), dim3(256), 0, stream>>>(cseq, kseq, embC, embR,
                                                        inter);
  gemm_xg<<<dim3(8, 256), dim3(256), 0, stream>>>(inter, wihb, b_ih, b_hh, xg);
  lstm_kernel<<<dim3(32), dim3(256), 0, stream>>>(W_hh, xg, hbuf_hi, hbuf_lo,
                                                  lstm, flags);
  score_kernel<<<dim3(256), dim3(512), 0, stream>>>(lstm, mlpwb, mlp_b, sim_W,
                                                    score);
  attn_kernel<<<dim3(64), dim3(256), 0, stream>>>(score, lstm, attno);
  gemm_fc<<<dim3(8, 256), dim3(256), 0, stream>>>(attno, lstm, fcwb, fcw1lo,
                                                  fc_b, pbuf, qbuf);
  scan_pq<<<dim3(4, 64), dim3(256), 0, stream>>>(pbuf, qbuf);
}